// Round 9
// baseline (634.100 us; speedup 1.0000x reference)
//
#include <hip/hip_runtime.h>

#define NN 100000
#define NE 1600000
#define HID 64
#define TXT 384
#define BATCH 1024
#define NBUCK 391        // ceil(NN/256)
#define SBLK 256         // scatter/hist blocks
#define EPB ((NE + SBLK - 1) / SBLK)   // edges per block = 6250
#define NTILE 6250       // NN/16 exactly
#define LDK2 72          // k_layer bf16 stride (144 B)

typedef __attribute__((ext_vector_type(8))) short short8;
typedef __attribute__((ext_vector_type(4))) float float4v;

__device__ __forceinline__ ushort f2bf(float f) {
  unsigned u = __float_as_uint(f);
  unsigned r = (u + 0x7fffu + ((u >> 16) & 1u)) >> 16;  // round-to-nearest-even
  return (ushort)r;
}
__device__ __forceinline__ float bf2f(ushort u) {
  return __uint_as_float(((unsigned)u) << 16);
}

// ---- P1: per-(block,bucket) histogram matrix --------------------------------
__global__ void k_hist2(const int* __restrict__ src, const int* __restrict__ dst,
                        int* __restrict__ cm_f, int* __restrict__ cm_r) {
  __shared__ int hf[NBUCK], hr[NBUCK];
  const int t = threadIdx.x, blk = blockIdx.x;
  for (int i = t; i < NBUCK; i += 256) { hf[i] = 0; hr[i] = 0; }
  __syncthreads();
  const int e0 = blk * EPB, e1 = min(NE, e0 + EPB);
  for (int e = e0 + t; e < e1; e += 256) {
    atomicAdd(&hf[dst[e] >> 8], 1);
    atomicAdd(&hr[src[e] >> 8], 1);
  }
  __syncthreads();
  for (int i = t; i < NBUCK; i += 256) {
    cm_f[i * SBLK + blk] = hf[i];
    cm_r[i * SBLK + blk] = hr[i];
  }
}

// ---- P2a: per-bucket exclusive scan over the 256 block-counts ---------------
__global__ void k_scan1(int* __restrict__ cm_f, int* __restrict__ cm_r,
                        int* __restrict__ btot) {
  __shared__ int tmp[256];
  const int t = threadIdx.x;
  int b = blockIdx.x;
  int* cm = (b < NBUCK) ? cm_f : cm_r;
  int bucket = (b < NBUCK) ? b : b - NBUCK;
  int* row = cm + bucket * SBLK;
  int v = row[t];
  tmp[t] = v; __syncthreads();
  for (int d = 1; d < 256; d <<= 1) {
    int s = tmp[t]; if (t >= d) s += tmp[t - d];
    __syncthreads(); tmp[t] = s; __syncthreads();
  }
  row[t] = tmp[t] - v;
  if (t == 255) btot[b] = tmp[t];
}

// ---- P2b: exclusive scan of bucket totals -> bucket bases -------------------
__global__ void k_scan2(const int* __restrict__ btot,
                        int* __restrict__ bbase_f, int* __restrict__ bbase_r) {
  __shared__ int tmp[512];
  const int t = threadIdx.x;
  int h = (t < NBUCK) ? btot[t] : 0;
  tmp[t] = h; __syncthreads();
  for (int d = 1; d < 512; d <<= 1) {
    int v = tmp[t]; if (t >= d) v += tmp[t - d];
    __syncthreads(); tmp[t] = v; __syncthreads();
  }
  if (t < NBUCK) bbase_f[t] = tmp[t] - h;
  __syncthreads();
  h = (t < NBUCK) ? btot[NBUCK + t] : 0;
  tmp[t] = h; __syncthreads();
  for (int d = 1; d < 512; d <<= 1) {
    int v = tmp[t]; if (t >= d) v += tmp[t - d];
    __syncthreads(); tmp[t] = v; __syncthreads();
  }
  if (t < NBUCK) bbase_r[t] = tmp[t] - h;
}

// ---- P3: scatter with LDS cursors only (zero global atomics) ----------------
__global__ void k_scatter2(const int* __restrict__ src, const int* __restrict__ dst,
                           const float* __restrict__ w,
                           const int* __restrict__ cm_f, const int* __restrict__ cm_r,
                           const int* __restrict__ bbase_f, const int* __restrict__ bbase_r,
                           int2* __restrict__ stg_f, int2* __restrict__ stg_r) {
  __shared__ int cur_f[NBUCK], cur_r[NBUCK];
  const int t = threadIdx.x, blk = blockIdx.x;
  for (int i = t; i < NBUCK; i += 256) {
    cur_f[i] = bbase_f[i] + cm_f[i * SBLK + blk];
    cur_r[i] = bbase_r[i] + cm_r[i * SBLK + blk];
  }
  __syncthreads();
  const int e0 = blk * EPB, e1 = min(NE, e0 + EPB);
  for (int e = e0 + t; e < e1; e += 256) {
    int s = src[e], d = dst[e];
    int wb = __float_as_int(w[e]);
    int p = atomicAdd(&cur_f[d >> 8], 1);
    stg_f[p] = make_int2(((d & 255) << 24) | s, wb);
    int q = atomicAdd(&cur_r[s >> 8], 1);
    stg_r[q] = make_int2(((s & 255) << 24) | d, wb);
  }
}

// ---- P4: per-bucket CSR finalize --------------------------------------------
__global__ void p_build(const int2* __restrict__ stgf, const int* __restrict__ btotf,
                        const int* __restrict__ bbasef,
                        int* __restrict__ startf, int* __restrict__ cntf,
                        int2* __restrict__ cvf,
                        const int2* __restrict__ stgr, const int* __restrict__ btotr,
                        const int* __restrict__ bbaser,
                        int* __restrict__ startr, int* __restrict__ cntr,
                        int2* __restrict__ cvr) {
  int b = blockIdx.x;
  const int2* stg; const int* bcnt; const int* bbase;
  int* start; int* cnt; int2* cv;
  if (b < NBUCK) { stg = stgf; bcnt = btotf; bbase = bbasef; start = startf; cnt = cntf; cv = cvf; }
  else { b -= NBUCK; stg = stgr; bcnt = btotr; bbase = bbaser; start = startr; cnt = cntr; cv = cvr; }
  const int base = bbase[b];
  const int n = bcnt[b];
  const int t = threadIdx.x;
  __shared__ int hist[256], tmp[256], cur[256];
  hist[t] = 0;
  __syncthreads();
  for (int i = t; i < n; i += 256) {
    unsigned pk = (unsigned)stg[base + i].x;
    atomicAdd(&hist[pk >> 24], 1);
  }
  __syncthreads();
  const int h = hist[t];
  tmp[t] = h; __syncthreads();
  for (int d = 1; d < 256; d <<= 1) {
    int v = tmp[t]; if (t >= d) v += tmp[t - d];
    __syncthreads(); tmp[t] = v; __syncthreads();
  }
  const int excl = tmp[t] - h;
  const int node = (b << 8) + t;
  if (node < NN) { start[node] = base + excl; cnt[node] = h; }
  cur[t] = excl;
  __syncthreads();
  for (int i = t; i < n; i += 256) {
    int2 en = stg[base + i];
    unsigned d8 = ((unsigned)en.x) >> 24;
    int pos = atomicAdd(&cur[d8], 1);
    cv[base + pos] = make_int2(en.x & 0xFFFFFF, en.y);
  }
}

// ---- weighted-mean aggregation, BOTH directions in one dispatch -------------
__global__ void k_gather2(const ushort* __restrict__ xb,
                          const int* __restrict__ startf, const int* __restrict__ cntf,
                          const int2* __restrict__ cvf, ushort* __restrict__ nbf,
                          const int* __restrict__ startr, const int* __restrict__ cntr,
                          const int2* __restrict__ cvr, ushort* __restrict__ nbr) {
  const int GBc = ((NN * 32) + 255) / 256;
  int b = blockIdx.x;
  const int* start; const int* cnt; const int2* cv; ushort* outp;
  if (b < GBc) { start = startf; cnt = cntf; cv = cvf; outp = nbf; }
  else { b -= GBc; start = startr; cnt = cntr; cv = cvr; outp = nbr; }
  int t = b * 256 + threadIdx.x;
  int row = t >> 5;
  int l2 = (t & 31) * 2;
  if (row >= NN) return;
  int s = start[row];
  int c = cnt[row];
  int e = s + c;
  float ax = 0.f, ay = 0.f;
  int j = s;
  for (; j + 4 <= e; j += 4) {
    int2 e0 = cv[j], e1 = cv[j + 1], e2 = cv[j + 2], e3 = cv[j + 3];
    uint v0 = *(const uint*)(xb + (size_t)e0.x * 64 + l2);
    uint v1 = *(const uint*)(xb + (size_t)e1.x * 64 + l2);
    uint v2 = *(const uint*)(xb + (size_t)e2.x * 64 + l2);
    uint v3 = *(const uint*)(xb + (size_t)e3.x * 64 + l2);
    float w0 = __int_as_float(e0.y), w1 = __int_as_float(e1.y);
    float w2 = __int_as_float(e2.y), w3 = __int_as_float(e3.y);
    ax += w0 * bf2f((ushort)v0); ay += w0 * bf2f((ushort)(v0 >> 16));
    ax += w1 * bf2f((ushort)v1); ay += w1 * bf2f((ushort)(v1 >> 16));
    ax += w2 * bf2f((ushort)v2); ay += w2 * bf2f((ushort)(v2 >> 16));
    ax += w3 * bf2f((ushort)v3); ay += w3 * bf2f((ushort)(v3 >> 16));
  }
  for (; j < e; ++j) {
    int2 ee = cv[j];
    uint v = *(const uint*)(xb + (size_t)ee.x * 64 + l2);
    float ww = __int_as_float(ee.y);
    ax += ww * bf2f((ushort)v); ay += ww * bf2f((ushort)(v >> 16));
  }
  float inv = (c > 0) ? 1.0f / (float)c : 0.f;   // DGL mean; zero in-degree -> 0
  uint pv = (uint)f2bf(ax * inv) | ((uint)f2bf(ay * inv) << 16);
  *(uint*)(outp + (size_t)row * 64 + l2) = pv;
}

// ---- A pre-tile: T fp32 -> At bf16 in MFMA A-fragment layout ----------------
// At[((tile*12 + ch)*64 + quad*16 + lr)*8 + j] = bf16(T[tile*16+lr][ch*32+quad*8+j])
// Thread g handles (row = g/12, ch = g%12): reads bytes [g*128, g*128+128) of T
// -> the whole grid reads T perfectly sequentially.
__global__ void k_atile(const float* __restrict__ T, ushort* __restrict__ At) {
  int g = blockIdx.x * 256 + threadIdx.x;
  if (g >= NN * 12) return;
  int row = (int)((unsigned)g / 12u);
  int ch = g - row * 12;
  const float* p = T + (size_t)g * 32;   // == T + row*384 + ch*32
  ushort* dst = At + (((size_t)(row >> 4) * 12 + ch) * 64 + (row & 15)) * 8;
  #pragma unroll
  for (int q = 0; q < 4; ++q) {
    float4 a = *(const float4*)(p + q * 8);
    float4 b = *(const float4*)(p + q * 8 + 4);
    short8 s;
    s[0] = (short)f2bf(a.x); s[1] = (short)f2bf(a.y);
    s[2] = (short)f2bf(a.z); s[3] = (short)f2bf(a.w);
    s[4] = (short)f2bf(b.x); s[5] = (short)f2bf(b.y);
    s[6] = (short)f2bf(b.z); s[7] = (short)f2bf(b.w);
    *(short8*)(dst + q * 128) = s;   // quad stride = 16 lanes * 8 shorts
  }
}

// ---- W pre-tile: W fp32 [k][n] -> Wt bf16 in MFMA B-fragment layout ---------
// Wt[((ch*4+nt)*64 + lane)*8 + j] = bf16(W[(ch*32+quad*8+j)*64 + nt*16+lr])
__global__ void k_wtile(const float* __restrict__ W, ushort* __restrict__ Wt) {
  int b = blockIdx.x;            // 48 blocks: ch = b>>2, nt = b&3
  int ch = b >> 2, nt = b & 3;
  int lane = threadIdx.x;        // 64
  int quad = lane >> 4, lr = lane & 15;
  short8 s;
  #pragma unroll
  for (int j = 0; j < 8; ++j)
    s[j] = (short)f2bf(W[(ch * 32 + quad * 8 + j) * 64 + nt * 16 + lr]);
  *(short8*)&Wt[((size_t)b * 64 + lane) * 8] = s;
}

// ---- encoder GEMM v2: zero LDS, zero barriers, all-coalesced fragment loads -
// wave = 2 row-tiles (32 rows); block = 4 waves = 128 rows; 782 blocks.
__launch_bounds__(256)
__global__ void k_enc2(const ushort* __restrict__ At, const ushort* __restrict__ Wt,
                       const float* __restrict__ bias,
                       float* __restrict__ x, ushort* __restrict__ xb) {
  const int tid = threadIdx.x;
  const int wave = tid >> 6, lane = tid & 63;
  const int quad = lane >> 4, lr = lane & 15;
  const int t0 = blockIdx.x * 8 + wave * 2;      // tile pair
  const int t0c = min(t0, NTILE - 1), t1c = min(t0 + 1, NTILE - 1);
  const ushort* pa0 = At + (size_t)t0c * 12 * 512 + lane * 8;
  const ushort* pa1 = At + (size_t)t1c * 12 * 512 + lane * 8;
  const ushort* pw = Wt + lane * 8;
  float4v acc[2][4] = {};
  #pragma unroll
  for (int ch = 0; ch < 12; ++ch) {
    short8 af0 = *(const short8*)(pa0 + ch * 512);
    short8 af1 = *(const short8*)(pa1 + ch * 512);
    #pragma unroll
    for (int nt = 0; nt < 4; ++nt) {
      short8 bfrag = *(const short8*)(pw + (ch * 4 + nt) * 512);
      acc[0][nt] = __builtin_amdgcn_mfma_f32_16x16x32_bf16(af0, bfrag, acc[0][nt], 0, 0, 0);
      acc[1][nt] = __builtin_amdgcn_mfma_f32_16x16x32_bf16(af1, bfrag, acc[1][nt], 0, 0, 0);
    }
  }
  #pragma unroll
  for (int nt = 0; nt < 4; ++nt) {
    const int col = nt * 16 + lr;
    const float bcol = bias[col];
    #pragma unroll
    for (int mt = 0; mt < 2; ++mt) {
      #pragma unroll
      for (int r = 0; r < 4; ++r) {
        const int row = (t0 + mt) * 16 + quad * 4 + r;
        if (row < NN) {
          float v = acc[mt][nt][r] + bcol;
          x[(size_t)row * 64 + col] = v;
          xb[(size_t)row * 64 + col] = f2bf(v);
        }
      }
    }
  }
}

// ---- fused per-layer combine: x += relu(xb@Wsf + nbf@Wnf + bf)
//                                  + relu(xb@Wsr + nbr@Wnr + br);  xb = bf16(x)
__launch_bounds__(256)
__global__ void k_layer(const ushort* __restrict__ xbin,
                        const ushort* __restrict__ nbf, const ushort* __restrict__ nbr,
                        const float* __restrict__ Wsf, const float* __restrict__ Wnf,
                        const float* __restrict__ bfv,
                        const float* __restrict__ Wsr, const float* __restrict__ Wnr,
                        const float* __restrict__ brv,
                        float* __restrict__ x, ushort* __restrict__ xb) {
  __shared__ short B4[4 * 64 * LDK2];   // Wsf, Wsr, Wnf, Wnr bf16 [n][k] (36 KB)
  __shared__ short As[128 * LDK2];      // one bf16 A tile (18 KB)
  const int tid = threadIdx.x;
  const int row0 = blockIdx.x * 128;
  const int wave = tid >> 6, lane = tid & 63;
  const int quad = lane >> 4, lr = lane & 15;

  {
    const float* wm0 = Wsf; const float* wm1 = Wsr;
    const float* wm2 = Wnf; const float* wm3 = Wnr;
    #pragma unroll
    for (int j = 0; j < 16; ++j) {
      int idx = j * 256 + tid;
      int k = idx >> 6, n = idx & 63;
      B4[0 * 64 * LDK2 + n * LDK2 + k] = (short)f2bf(wm0[idx]);
      B4[1 * 64 * LDK2 + n * LDK2 + k] = (short)f2bf(wm1[idx]);
      B4[2 * 64 * LDK2 + n * LDK2 + k] = (short)f2bf(wm2[idx]);
      B4[3 * 64 * LDK2 + n * LDK2 + k] = (short)f2bf(wm3[idx]);
    }
  }
  const int srow = tid >> 1, half = (tid & 1) * 32;
  const int grow = min(row0 + srow, NN - 1);
  {
    const uint4* s = (const uint4*)(xbin + (size_t)grow * 64 + half);
    uint4* d = (uint4*)&As[srow * LDK2 + half];
    d[0] = s[0]; d[1] = s[1]; d[2] = s[2]; d[3] = s[3];
  }
  const uint4* pf = (const uint4*)(nbf + (size_t)grow * 64 + half);
  uint4 p0 = pf[0], p1 = pf[1], p2 = pf[2], p3 = pf[3];
  __syncthreads();

  float4v accf[2][4] = {}, accr[2][4] = {};
  #pragma unroll
  for (int kk = 0; kk < 64; kk += 32) {
    short8 a0 = *(const short8*)&As[(wave * 32 + lr) * LDK2 + kk + quad * 8];
    short8 a1 = *(const short8*)&As[(wave * 32 + 16 + lr) * LDK2 + kk + quad * 8];
    #pragma unroll
    for (int nt = 0; nt < 4; ++nt) {
      short8 bs = *(const short8*)&B4[0 * 64 * LDK2 + (nt * 16 + lr) * LDK2 + kk + quad * 8];
      accf[0][nt] = __builtin_amdgcn_mfma_f32_16x16x32_bf16(a0, bs, accf[0][nt], 0, 0, 0);
      accf[1][nt] = __builtin_amdgcn_mfma_f32_16x16x32_bf16(a1, bs, accf[1][nt], 0, 0, 0);
      short8 bq = *(const short8*)&B4[1 * 64 * LDK2 + (nt * 16 + lr) * LDK2 + kk + quad * 8];
      accr[0][nt] = __builtin_amdgcn_mfma_f32_16x16x32_bf16(a0, bq, accr[0][nt], 0, 0, 0);
      accr[1][nt] = __builtin_amdgcn_mfma_f32_16x16x32_bf16(a1, bq, accr[1][nt], 0, 0, 0);
    }
  }
  __syncthreads();
  { uint4* d = (uint4*)&As[srow * LDK2 + half]; d[0] = p0; d[1] = p1; d[2] = p2; d[3] = p3; }
  {
    const uint4* pr = (const uint4*)(nbr + (size_t)grow * 64 + half);
    p0 = pr[0]; p1 = pr[1]; p2 = pr[2]; p3 = pr[3];
  }
  __syncthreads();
  #pragma unroll
  for (int kk = 0; kk < 64; kk += 32) {
    short8 a0 = *(const short8*)&As[(wave * 32 + lr) * LDK2 + kk + quad * 8];
    short8 a1 = *(const short8*)&As[(wave * 32 + 16 + lr) * LDK2 + kk + quad * 8];
    #pragma unroll
    for (int nt = 0; nt < 4; ++nt) {
      short8 bs = *(const short8*)&B4[2 * 64 * LDK2 + (nt * 16 + lr) * LDK2 + kk + quad * 8];
      accf[0][nt] = __builtin_amdgcn_mfma_f32_16x16x32_bf16(a0, bs, accf[0][nt], 0, 0, 0);
      accf[1][nt] = __builtin_amdgcn_mfma_f32_16x16x32_bf16(a1, bs, accf[1][nt], 0, 0, 0);
    }
  }
  __syncthreads();
  { uint4* d = (uint4*)&As[srow * LDK2 + half]; d[0] = p0; d[1] = p1; d[2] = p2; d[3] = p3; }
  __syncthreads();
  #pragma unroll
  for (int kk = 0; kk < 64; kk += 32) {
    short8 a0 = *(const short8*)&As[(wave * 32 + lr) * LDK2 + kk + quad * 8];
    short8 a1 = *(const short8*)&As[(wave * 32 + 16 + lr) * LDK2 + kk + quad * 8];
    #pragma unroll
    for (int nt = 0; nt < 4; ++nt) {
      short8 bs = *(const short8*)&B4[3 * 64 * LDK2 + (nt * 16 + lr) * LDK2 + kk + quad * 8];
      accr[0][nt] = __builtin_amdgcn_mfma_f32_16x16x32_bf16(a0, bs, accr[0][nt], 0, 0, 0);
      accr[1][nt] = __builtin_amdgcn_mfma_f32_16x16x32_bf16(a1, bs, accr[1][nt], 0, 0, 0);
    }
  }
  #pragma unroll
  for (int nt = 0; nt < 4; ++nt) {
    const int col = nt * 16 + lr;
    const float bf_c = bfv[col], br_c = brv[col];
    #pragma unroll
    for (int mt = 0; mt < 2; ++mt) {
      #pragma unroll
      for (int r = 0; r < 4; ++r) {
        const int row = row0 + wave * 32 + mt * 16 + quad * 4 + r;
        if (row < NN) {
          size_t idx = (size_t)row * 64 + col;
          float v = x[idx] + fmaxf(accf[mt][nt][r] + bf_c, 0.f)
                           + fmaxf(accr[mt][nt][r] + br_c, 0.f);
          x[idx] = v;
          xb[idx] = f2bf(v);
        }
      }
    }
  }
}

// ---- output gather + L2 normalize -------------------------------------------
__global__ void k_out(const float* __restrict__ x, const int* __restrict__ ids,
                      float* __restrict__ out) {
  int b = (blockIdx.x * blockDim.x + threadIdx.x) >> 6;
  int lane = threadIdx.x & 63;
  if (b >= BATCH) return;
  int row = ids[b];
  float v = x[(size_t)row * 64 + lane];
  float s = v * v;
  #pragma unroll
  for (int m = 1; m < 64; m <<= 1) s += __shfl_xor(s, m);
  out[b * 64 + lane] = v / sqrtf(s);
}

extern "C" void kernel_launch(void* const* d_in, const int* in_sizes, int n_in,
                              void* d_out, int out_size, void* d_ws, size_t ws_size,
                              hipStream_t stream) {
  const float* text = (const float*)d_in[0];
  const float* wts  = (const float*)d_in[1];
  const float* Wenc = (const float*)d_in[2];
  const float* benc = (const float*)d_in[3];
  const float* Wsf  = (const float*)d_in[4];
  const float* Wnf  = (const float*)d_in[5];
  const float* bf   = (const float*)d_in[6];
  const float* Wsr  = (const float*)d_in[7];
  const float* Wnr  = (const float*)d_in[8];
  const float* br   = (const float*)d_in[9];
  const int*   src  = (const int*)d_in[10];
  const int*   dst  = (const int*)d_in[11];
  const int*   ids  = (const int*)d_in[12];
  float* out = (float*)d_out;

  char* ws = (char*)d_ws;
  size_t o = 0;
  auto alloc = [&](size_t f32elems) {
    void* p = ws + o;
    o += f32elems * 4;
    o = (o + 255) & ~(size_t)255;
    return p;
  };
  float*  x   = (float*)alloc((size_t)NN * 64);
  ushort* xb  = (ushort*)alloc((size_t)NN * 32);  // bf16 mirror of x
  ushort* nbf = (ushort*)alloc((size_t)NN * 32);  // bf16 neigh fwd; aliased stage_f
  ushort* nbr = (ushort*)alloc((size_t)NN * 32);  // bf16 neigh rev; aliased stage_r
  ushort* At  = (ushort*)alloc((size_t)NTILE * 12 * 512 / 2);  // tiled bf16 text (76.8 MB)
  ushort* Wt  = (ushort*)alloc(48 * 512 / 2);                  // tiled bf16 W_enc (48 KB)
  int2*   cvf = (int2*)alloc((size_t)NE * 2);     // final CSR (col, weight)
  int2*   cvr = (int2*)alloc((size_t)NE * 2);
  int* cm_f    = (int*)alloc((size_t)NBUCK * SBLK);
  int* cm_r    = (int*)alloc((size_t)NBUCK * SBLK);
  int* btot    = (int*)alloc(2 * NBUCK);
  int* bbase_f = (int*)alloc(NBUCK);
  int* bbase_r = (int*)alloc(NBUCK);
  int* startf  = (int*)alloc(NN);
  int* cntf    = (int*)alloc(NN);
  int* startr  = (int*)alloc(NN);
  int* cntr    = (int*)alloc(NN);

  int2* stg_f = (int2*)nbf;   // staging dead before gathers write nbf
  int2* stg_r = (int2*)nbr;

  const int EB2 = (NN + 127) / 128;   // 782 blocks (MFMA kernels)

  // encoder pre-tiling (independent of CSR build)
  k_wtile<<<48, 64, 0, stream>>>(Wenc, Wt);
  k_atile<<<(NN * 12 + 255) / 256, 256, 0, stream>>>(text, At);

  k_hist2<<<SBLK, 256, 0, stream>>>(src, dst, cm_f, cm_r);
  k_scan1<<<2 * NBUCK, 256, 0, stream>>>(cm_f, cm_r, btot);
  k_scan2<<<1, 512, 0, stream>>>(btot, bbase_f, bbase_r);
  k_scatter2<<<SBLK, 256, 0, stream>>>(src, dst, wts, cm_f, cm_r,
                                       bbase_f, bbase_r, stg_f, stg_r);
  p_build<<<2 * NBUCK, 256, 0, stream>>>(stg_f, btot, bbase_f, startf, cntf, cvf,
                                         stg_r, btot + NBUCK, bbase_r, startr, cntr, cvr);
  k_enc2<<<EB2, 256, 0, stream>>>(At, Wt, benc, x, xb);

  const int GB = ((NN * 32) + 255) / 256;   // 12500 blocks per direction
  for (int l = 0; l < 2; ++l) {
    k_gather2<<<2 * GB, 256, 0, stream>>>(xb, startf, cntf, cvf, nbf,
                                          startr, cntr, cvr, nbr);
    k_layer<<<EB2, 256, 0, stream>>>(xb, nbf, nbr,
                                     Wsf + l * HID * HID, Wnf + l * HID * HID, bf + l * HID,
                                     Wsr + l * HID * HID, Wnr + l * HID * HID, br + l * HID,
                                     x, xb);
  }
  k_out<<<(BATCH * 64) / 256, 256, 0, stream>>>(x, ids, out);
}

// Round 10
// 614.508 us; speedup vs baseline: 1.0319x; 1.0319x over previous
//
#include <hip/hip_runtime.h>

#define NN 100000
#define NE 1600000
#define HID 64
#define TXT 384
#define BATCH 1024
#define NBUCK 391        // ceil(NN/256)
#define SBLK 256         // scatter/hist blocks
#define EPB ((NE + SBLK - 1) / SBLK)   // edges per block = 6250
#define LDA 40           // k_enc A-tile bf16 stride (80 B)
#define LDK2 72          // k_layer bf16 stride (144 B)

typedef __attribute__((ext_vector_type(8))) short short8;
typedef __attribute__((ext_vector_type(4))) float float4v;

__device__ __forceinline__ ushort f2bf(float f) {
  unsigned u = __float_as_uint(f);
  unsigned r = (u + 0x7fffu + ((u >> 16) & 1u)) >> 16;  // round-to-nearest-even
  return (ushort)r;
}
__device__ __forceinline__ float bf2f(ushort u) {
  return __uint_as_float(((unsigned)u) << 16);
}
__device__ __forceinline__ short8 pack8(float4 a, float4 b) {
  short8 s;
  s[0] = (short)f2bf(a.x); s[1] = (short)f2bf(a.y);
  s[2] = (short)f2bf(a.z); s[3] = (short)f2bf(a.w);
  s[4] = (short)f2bf(b.x); s[5] = (short)f2bf(b.y);
  s[6] = (short)f2bf(b.z); s[7] = (short)f2bf(b.w);
  return s;
}

// ---- P1: per-(block,bucket) histogram matrix --------------------------------
__global__ void k_hist2(const int* __restrict__ src, const int* __restrict__ dst,
                        int* __restrict__ cm_f, int* __restrict__ cm_r) {
  __shared__ int hf[NBUCK], hr[NBUCK];
  const int t = threadIdx.x, blk = blockIdx.x;
  for (int i = t; i < NBUCK; i += 256) { hf[i] = 0; hr[i] = 0; }
  __syncthreads();
  const int e0 = blk * EPB, e1 = min(NE, e0 + EPB);
  for (int e = e0 + t; e < e1; e += 256) {
    atomicAdd(&hf[dst[e] >> 8], 1);
    atomicAdd(&hr[src[e] >> 8], 1);
  }
  __syncthreads();
  for (int i = t; i < NBUCK; i += 256) {
    cm_f[i * SBLK + blk] = hf[i];
    cm_r[i * SBLK + blk] = hr[i];
  }
}

// ---- P2a: per-bucket exclusive scan over the 256 block-counts ---------------
__global__ void k_scan1(int* __restrict__ cm_f, int* __restrict__ cm_r,
                        int* __restrict__ btot) {
  __shared__ int tmp[256];
  const int t = threadIdx.x;
  int b = blockIdx.x;
  int* cm = (b < NBUCK) ? cm_f : cm_r;
  int bucket = (b < NBUCK) ? b : b - NBUCK;
  int* row = cm + bucket * SBLK;
  int v = row[t];
  tmp[t] = v; __syncthreads();
  for (int d = 1; d < 256; d <<= 1) {
    int s = tmp[t]; if (t >= d) s += tmp[t - d];
    __syncthreads(); tmp[t] = s; __syncthreads();
  }
  row[t] = tmp[t] - v;
  if (t == 255) btot[b] = tmp[t];
}

// ---- P2b: exclusive scan of bucket totals -> bucket bases -------------------
__global__ void k_scan2(const int* __restrict__ btot,
                        int* __restrict__ bbase_f, int* __restrict__ bbase_r) {
  __shared__ int tmp[512];
  const int t = threadIdx.x;
  int h = (t < NBUCK) ? btot[t] : 0;
  tmp[t] = h; __syncthreads();
  for (int d = 1; d < 512; d <<= 1) {
    int v = tmp[t]; if (t >= d) v += tmp[t - d];
    __syncthreads(); tmp[t] = v; __syncthreads();
  }
  if (t < NBUCK) bbase_f[t] = tmp[t] - h;
  __syncthreads();
  h = (t < NBUCK) ? btot[NBUCK + t] : 0;
  tmp[t] = h; __syncthreads();
  for (int d = 1; d < 512; d <<= 1) {
    int v = tmp[t]; if (t >= d) v += tmp[t - d];
    __syncthreads(); tmp[t] = v; __syncthreads();
  }
  if (t < NBUCK) bbase_r[t] = tmp[t] - h;
}

// ---- P3: scatter with LDS cursors only (zero global atomics) ----------------
__global__ void k_scatter2(const int* __restrict__ src, const int* __restrict__ dst,
                           const float* __restrict__ w,
                           const int* __restrict__ cm_f, const int* __restrict__ cm_r,
                           const int* __restrict__ bbase_f, const int* __restrict__ bbase_r,
                           int2* __restrict__ stg_f, int2* __restrict__ stg_r) {
  __shared__ int cur_f[NBUCK], cur_r[NBUCK];
  const int t = threadIdx.x, blk = blockIdx.x;
  for (int i = t; i < NBUCK; i += 256) {
    cur_f[i] = bbase_f[i] + cm_f[i * SBLK + blk];
    cur_r[i] = bbase_r[i] + cm_r[i * SBLK + blk];
  }
  __syncthreads();
  const int e0 = blk * EPB, e1 = min(NE, e0 + EPB);
  for (int e = e0 + t; e < e1; e += 256) {
    int s = src[e], d = dst[e];
    int wb = __float_as_int(w[e]);
    int p = atomicAdd(&cur_f[d >> 8], 1);
    stg_f[p] = make_int2(((d & 255) << 24) | s, wb);
    int q = atomicAdd(&cur_r[s >> 8], 1);
    stg_r[q] = make_int2(((s & 255) << 24) | d, wb);
  }
}

// ---- P4: per-bucket CSR finalize --------------------------------------------
__global__ void p_build(const int2* __restrict__ stgf, const int* __restrict__ btotf,
                        const int* __restrict__ bbasef,
                        int* __restrict__ startf, int* __restrict__ cntf,
                        int2* __restrict__ cvf,
                        const int2* __restrict__ stgr, const int* __restrict__ btotr,
                        const int* __restrict__ bbaser,
                        int* __restrict__ startr, int* __restrict__ cntr,
                        int2* __restrict__ cvr) {
  int b = blockIdx.x;
  const int2* stg; const int* bcnt; const int* bbase;
  int* start; int* cnt; int2* cv;
  if (b < NBUCK) { stg = stgf; bcnt = btotf; bbase = bbasef; start = startf; cnt = cntf; cv = cvf; }
  else { b -= NBUCK; stg = stgr; bcnt = btotr; bbase = bbaser; start = startr; cnt = cntr; cv = cvr; }
  const int base = bbase[b];
  const int n = bcnt[b];
  const int t = threadIdx.x;
  __shared__ int hist[256], tmp[256], cur[256];
  hist[t] = 0;
  __syncthreads();
  for (int i = t; i < n; i += 256) {
    unsigned pk = (unsigned)stg[base + i].x;
    atomicAdd(&hist[pk >> 24], 1);
  }
  __syncthreads();
  const int h = hist[t];
  tmp[t] = h; __syncthreads();
  for (int d = 1; d < 256; d <<= 1) {
    int v = tmp[t]; if (t >= d) v += tmp[t - d];
    __syncthreads(); tmp[t] = v; __syncthreads();
  }
  const int excl = tmp[t] - h;
  const int node = (b << 8) + t;
  if (node < NN) { start[node] = base + excl; cnt[node] = h; }
  cur[t] = excl;
  __syncthreads();
  for (int i = t; i < n; i += 256) {
    int2 en = stg[base + i];
    unsigned d8 = ((unsigned)en.x) >> 24;
    int pos = atomicAdd(&cur[d8], 1);
    cv[base + pos] = make_int2(en.x & 0xFFFFFF, en.y);
  }
}

// ---- weighted-mean aggregation, BOTH directions in one dispatch -------------
__global__ void k_gather2(const ushort* __restrict__ xb,
                          const int* __restrict__ startf, const int* __restrict__ cntf,
                          const int2* __restrict__ cvf, ushort* __restrict__ nbf,
                          const int* __restrict__ startr, const int* __restrict__ cntr,
                          const int2* __restrict__ cvr, ushort* __restrict__ nbr) {
  const int GBc = ((NN * 32) + 255) / 256;
  int b = blockIdx.x;
  const int* start; const int* cnt; const int2* cv; ushort* outp;
  if (b < GBc) { start = startf; cnt = cntf; cv = cvf; outp = nbf; }
  else { b -= GBc; start = startr; cnt = cntr; cv = cvr; outp = nbr; }
  int t = b * 256 + threadIdx.x;
  int row = t >> 5;
  int l2 = (t & 31) * 2;
  if (row >= NN) return;
  int s = start[row];
  int c = cnt[row];
  int e = s + c;
  float ax = 0.f, ay = 0.f;
  int j = s;
  for (; j + 4 <= e; j += 4) {
    int2 e0 = cv[j], e1 = cv[j + 1], e2 = cv[j + 2], e3 = cv[j + 3];
    uint v0 = *(const uint*)(xb + (size_t)e0.x * 64 + l2);
    uint v1 = *(const uint*)(xb + (size_t)e1.x * 64 + l2);
    uint v2 = *(const uint*)(xb + (size_t)e2.x * 64 + l2);
    uint v3 = *(const uint*)(xb + (size_t)e3.x * 64 + l2);
    float w0 = __int_as_float(e0.y), w1 = __int_as_float(e1.y);
    float w2 = __int_as_float(e2.y), w3 = __int_as_float(e3.y);
    ax += w0 * bf2f((ushort)v0); ay += w0 * bf2f((ushort)(v0 >> 16));
    ax += w1 * bf2f((ushort)v1); ay += w1 * bf2f((ushort)(v1 >> 16));
    ax += w2 * bf2f((ushort)v2); ay += w2 * bf2f((ushort)(v2 >> 16));
    ax += w3 * bf2f((ushort)v3); ay += w3 * bf2f((ushort)(v3 >> 16));
  }
  for (; j < e; ++j) {
    int2 ee = cv[j];
    uint v = *(const uint*)(xb + (size_t)ee.x * 64 + l2);
    float ww = __int_as_float(ee.y);
    ax += ww * bf2f((ushort)v); ay += ww * bf2f((ushort)(v >> 16));
  }
  float inv = (c > 0) ? 1.0f / (float)c : 0.f;   // DGL mean; zero in-degree -> 0
  uint pv = (uint)f2bf(ax * inv) | ((uint)f2bf(ay * inv) << 16);
  *(uint*)(outp + (size_t)row * 64 + l2) = pv;
}

// ---- W pre-tile: W fp32 [k][n] -> Wt bf16 in MFMA B-fragment layout ---------
// Wt[((ch*4+nt)*64 + lane)*8 + j] = bf16(W[(ch*32+quad*8+j)*64 + nt*16+lr])
__global__ void k_wtile(const float* __restrict__ W, ushort* __restrict__ Wt) {
  int b = blockIdx.x;            // 48 blocks: ch = b>>2, nt = b&3
  int ch = b >> 2, nt = b & 3;
  int lane = threadIdx.x;        // 64
  int quad = lane >> 4, lr = lane & 15;
  short8 s;
  #pragma unroll
  for (int j = 0; j < 8; ++j)
    s[j] = (short)f2bf(W[(ch * 32 + quad * 8 + j) * 64 + nt * 16 + lr]);
  *(short8*)&Wt[((size_t)b * 64 + lane) * 8] = s;
}

// ---- encoder v3: A double-buffered in small LDS (20 KB), B fragments loaded
// coalesced from L2-resident Wt (no LDS, no extra barrier). One barrier/chunk;
// next chunk's 64 B/thread global loads issued right after the store -> they
// overlap MFMA + barrier. Occupancy ~6 blocks/CU -> enough loads in flight to
// stream T at HBM rate.
__launch_bounds__(256)
__global__ void k_enc3(const float* __restrict__ T, const ushort* __restrict__ Wt,
                       const float* __restrict__ bias,
                       float* __restrict__ x, ushort* __restrict__ xb) {
  __shared__ short As[2][128 * LDA];   // 2 x 10 KB
  const int tid = threadIdx.x;
  const int row0 = blockIdx.x * 128;
  const int wave = tid >> 6, lane = tid & 63;
  const int quad = lane >> 4, lr = lane & 15;
  const int srow = tid >> 1, shalf = (tid & 1) * 16;
  const int grow = min(row0 + srow, NN - 1);
  const float* tp = T + (size_t)grow * TXT + shalf;

  // chunk 0 -> As[0]; prefetch chunk 1 into regs
  float4 pa0 = *(const float4*)(tp);
  float4 pa1 = *(const float4*)(tp + 4);
  float4 pa2 = *(const float4*)(tp + 8);
  float4 pa3 = *(const float4*)(tp + 12);
  *(short8*)&As[0][srow * LDA + shalf] = pack8(pa0, pa1);
  *(short8*)&As[0][srow * LDA + shalf + 8] = pack8(pa2, pa3);
  pa0 = *(const float4*)(tp + 32);
  pa1 = *(const float4*)(tp + 36);
  pa2 = *(const float4*)(tp + 40);
  pa3 = *(const float4*)(tp + 44);
  __syncthreads();

  const ushort* pw = Wt + lane * 8;
  float4v acc[2][4] = {};
  #pragma unroll
  for (int ch = 0; ch < 12; ++ch) {
    const short* Ac = As[ch & 1];
    short8 af0 = *(const short8*)&Ac[(wave * 32 + lr) * LDA + quad * 8];
    short8 af1 = *(const short8*)&Ac[(wave * 32 + 16 + lr) * LDA + quad * 8];
    #pragma unroll
    for (int nt = 0; nt < 4; ++nt) {
      short8 bfrag = *(const short8*)(pw + (size_t)(ch * 4 + nt) * 512);
      acc[0][nt] = __builtin_amdgcn_mfma_f32_16x16x32_bf16(af0, bfrag, acc[0][nt], 0, 0, 0);
      acc[1][nt] = __builtin_amdgcn_mfma_f32_16x16x32_bf16(af1, bfrag, acc[1][nt], 0, 0, 0);
    }
    if (ch < 11) {
      short* An = As[(ch + 1) & 1];
      *(short8*)&An[srow * LDA + shalf] = pack8(pa0, pa1);
      *(short8*)&An[srow * LDA + shalf + 8] = pack8(pa2, pa3);
      if (ch + 2 < 12) {
        const float* q = tp + (ch + 2) * 32;
        pa0 = *(const float4*)(q);
        pa1 = *(const float4*)(q + 4);
        pa2 = *(const float4*)(q + 8);
        pa3 = *(const float4*)(q + 12);
      }
      __syncthreads();
    }
  }
  // epilogue
  #pragma unroll
  for (int nt = 0; nt < 4; ++nt) {
    const int col = nt * 16 + lr;
    const float bcol = bias[col];
    #pragma unroll
    for (int mt = 0; mt < 2; ++mt) {
      #pragma unroll
      for (int r = 0; r < 4; ++r) {
        const int row = row0 + wave * 32 + mt * 16 + quad * 4 + r;
        if (row < NN) {
          float v = acc[mt][nt][r] + bcol;
          x[(size_t)row * 64 + col] = v;
          xb[(size_t)row * 64 + col] = f2bf(v);
        }
      }
    }
  }
}

// ---- fused per-layer combine: x += relu(xb@Wsf + nbf@Wnf + bf)
//                                  + relu(xb@Wsr + nbr@Wnr + br);  xb = bf16(x)
__launch_bounds__(256)
__global__ void k_layer(const ushort* __restrict__ xbin,
                        const ushort* __restrict__ nbf, const ushort* __restrict__ nbr,
                        const float* __restrict__ Wsf, const float* __restrict__ Wnf,
                        const float* __restrict__ bfv,
                        const float* __restrict__ Wsr, const float* __restrict__ Wnr,
                        const float* __restrict__ brv,
                        float* __restrict__ x, ushort* __restrict__ xb) {
  __shared__ short B4[4 * 64 * LDK2];   // Wsf, Wsr, Wnf, Wnr bf16 [n][k] (36 KB)
  __shared__ short As[128 * LDK2];      // one bf16 A tile (18 KB)
  const int tid = threadIdx.x;
  const int row0 = blockIdx.x * 128;
  const int wave = tid >> 6, lane = tid & 63;
  const int quad = lane >> 4, lr = lane & 15;

  {
    const float* wm0 = Wsf; const float* wm1 = Wsr;
    const float* wm2 = Wnf; const float* wm3 = Wnr;
    #pragma unroll
    for (int j = 0; j < 16; ++j) {
      int idx = j * 256 + tid;
      int k = idx >> 6, n = idx & 63;
      B4[0 * 64 * LDK2 + n * LDK2 + k] = (short)f2bf(wm0[idx]);
      B4[1 * 64 * LDK2 + n * LDK2 + k] = (short)f2bf(wm1[idx]);
      B4[2 * 64 * LDK2 + n * LDK2 + k] = (short)f2bf(wm2[idx]);
      B4[3 * 64 * LDK2 + n * LDK2 + k] = (short)f2bf(wm3[idx]);
    }
  }
  const int srow = tid >> 1, half = (tid & 1) * 32;
  const int grow = min(row0 + srow, NN - 1);
  {
    const uint4* s = (const uint4*)(xbin + (size_t)grow * 64 + half);
    uint4* d = (uint4*)&As[srow * LDK2 + half];
    d[0] = s[0]; d[1] = s[1]; d[2] = s[2]; d[3] = s[3];
  }
  const uint4* pf = (const uint4*)(nbf + (size_t)grow * 64 + half);
  uint4 p0 = pf[0], p1 = pf[1], p2 = pf[2], p3 = pf[3];
  __syncthreads();

  float4v accf[2][4] = {}, accr[2][4] = {};
  #pragma unroll
  for (int kk = 0; kk < 64; kk += 32) {
    short8 a0 = *(const short8*)&As[(wave * 32 + lr) * LDK2 + kk + quad * 8];
    short8 a1 = *(const short8*)&As[(wave * 32 + 16 + lr) * LDK2 + kk + quad * 8];
    #pragma unroll
    for (int nt = 0; nt < 4; ++nt) {
      short8 bs = *(const short8*)&B4[0 * 64 * LDK2 + (nt * 16 + lr) * LDK2 + kk + quad * 8];
      accf[0][nt] = __builtin_amdgcn_mfma_f32_16x16x32_bf16(a0, bs, accf[0][nt], 0, 0, 0);
      accf[1][nt] = __builtin_amdgcn_mfma_f32_16x16x32_bf16(a1, bs, accf[1][nt], 0, 0, 0);
      short8 bq = *(const short8*)&B4[1 * 64 * LDK2 + (nt * 16 + lr) * LDK2 + kk + quad * 8];
      accr[0][nt] = __builtin_amdgcn_mfma_f32_16x16x32_bf16(a0, bq, accr[0][nt], 0, 0, 0);
      accr[1][nt] = __builtin_amdgcn_mfma_f32_16x16x32_bf16(a1, bq, accr[1][nt], 0, 0, 0);
    }
  }
  __syncthreads();
  { uint4* d = (uint4*)&As[srow * LDK2 + half]; d[0] = p0; d[1] = p1; d[2] = p2; d[3] = p3; }
  {
    const uint4* pr = (const uint4*)(nbr + (size_t)grow * 64 + half);
    p0 = pr[0]; p1 = pr[1]; p2 = pr[2]; p3 = pr[3];
  }
  __syncthreads();
  #pragma unroll
  for (int kk = 0; kk < 64; kk += 32) {
    short8 a0 = *(const short8*)&As[(wave * 32 + lr) * LDK2 + kk + quad * 8];
    short8 a1 = *(const short8*)&As[(wave * 32 + 16 + lr) * LDK2 + kk + quad * 8];
    #pragma unroll
    for (int nt = 0; nt < 4; ++nt) {
      short8 bs = *(const short8*)&B4[2 * 64 * LDK2 + (nt * 16 + lr) * LDK2 + kk + quad * 8];
      accf[0][nt] = __builtin_amdgcn_mfma_f32_16x16x32_bf16(a0, bs, accf[0][nt], 0, 0, 0);
      accf[1][nt] = __builtin_amdgcn_mfma_f32_16x16x32_bf16(a1, bs, accf[1][nt], 0, 0, 0);
    }
  }
  __syncthreads();
  { uint4* d = (uint4*)&As[srow * LDK2 + half]; d[0] = p0; d[1] = p1; d[2] = p2; d[3] = p3; }
  __syncthreads();
  #pragma unroll
  for (int kk = 0; kk < 64; kk += 32) {
    short8 a0 = *(const short8*)&As[(wave * 32 + lr) * LDK2 + kk + quad * 8];
    short8 a1 = *(const short8*)&As[(wave * 32 + 16 + lr) * LDK2 + kk + quad * 8];
    #pragma unroll
    for (int nt = 0; nt < 4; ++nt) {
      short8 bs = *(const short8*)&B4[3 * 64 * LDK2 + (nt * 16 + lr) * LDK2 + kk + quad * 8];
      accr[0][nt] = __builtin_amdgcn_mfma_f32_16x16x32_bf16(a0, bs, accr[0][nt], 0, 0, 0);
      accr[1][nt] = __builtin_amdgcn_mfma_f32_16x16x32_bf16(a1, bs, accr[1][nt], 0, 0, 0);
    }
  }
  #pragma unroll
  for (int nt = 0; nt < 4; ++nt) {
    const int col = nt * 16 + lr;
    const float bf_c = bfv[col], br_c = brv[col];
    #pragma unroll
    for (int mt = 0; mt < 2; ++mt) {
      #pragma unroll
      for (int r = 0; r < 4; ++r) {
        const int row = row0 + wave * 32 + mt * 16 + quad * 4 + r;
        if (row < NN) {
          size_t idx = (size_t)row * 64 + col;
          float v = x[idx] + fmaxf(accf[mt][nt][r] + bf_c, 0.f)
                           + fmaxf(accr[mt][nt][r] + br_c, 0.f);
          x[idx] = v;
          xb[idx] = f2bf(v);
        }
      }
    }
  }
}

// ---- output gather + L2 normalize -------------------------------------------
__global__ void k_out(const float* __restrict__ x, const int* __restrict__ ids,
                      float* __restrict__ out) {
  int b = (blockIdx.x * blockDim.x + threadIdx.x) >> 6;
  int lane = threadIdx.x & 63;
  if (b >= BATCH) return;
  int row = ids[b];
  float v = x[(size_t)row * 64 + lane];
  float s = v * v;
  #pragma unroll
  for (int m = 1; m < 64; m <<= 1) s += __shfl_xor(s, m);
  out[b * 64 + lane] = v / sqrtf(s);
}

extern "C" void kernel_launch(void* const* d_in, const int* in_sizes, int n_in,
                              void* d_out, int out_size, void* d_ws, size_t ws_size,
                              hipStream_t stream) {
  const float* text = (const float*)d_in[0];
  const float* wts  = (const float*)d_in[1];
  const float* Wenc = (const float*)d_in[2];
  const float* benc = (const float*)d_in[3];
  const float* Wsf  = (const float*)d_in[4];
  const float* Wnf  = (const float*)d_in[5];
  const float* bf   = (const float*)d_in[6];
  const float* Wsr  = (const float*)d_in[7];
  const float* Wnr  = (const float*)d_in[8];
  const float* br   = (const float*)d_in[9];
  const int*   src  = (const int*)d_in[10];
  const int*   dst  = (const int*)d_in[11];
  const int*   ids  = (const int*)d_in[12];
  float* out = (float*)d_out;

  char* ws = (char*)d_ws;
  size_t o = 0;
  auto alloc = [&](size_t f32elems) {
    void* p = ws + o;
    o += f32elems * 4;
    o = (o + 255) & ~(size_t)255;
    return p;
  };
  float*  x   = (float*)alloc((size_t)NN * 64);
  ushort* xb  = (ushort*)alloc((size_t)NN * 32);  // bf16 mirror of x
  ushort* nbf = (ushort*)alloc((size_t)NN * 32);  // bf16 neigh fwd; aliased stage_f
  ushort* nbr = (ushort*)alloc((size_t)NN * 32);  // bf16 neigh rev; aliased stage_r
  ushort* Wt  = (ushort*)alloc(48 * 512 / 2);     // tiled bf16 W_enc (48 KB)
  int2*   cvf = (int2*)alloc((size_t)NE * 2);     // final CSR (col, weight)
  int2*   cvr = (int2*)alloc((size_t)NE * 2);
  int* cm_f    = (int*)alloc((size_t)NBUCK * SBLK);
  int* cm_r    = (int*)alloc((size_t)NBUCK * SBLK);
  int* btot    = (int*)alloc(2 * NBUCK);
  int* bbase_f = (int*)alloc(NBUCK);
  int* bbase_r = (int*)alloc(NBUCK);
  int* startf  = (int*)alloc(NN);
  int* cntf    = (int*)alloc(NN);
  int* startr  = (int*)alloc(NN);
  int* cntr    = (int*)alloc(NN);

  int2* stg_f = (int2*)nbf;   // staging dead before gathers write nbf
  int2* stg_r = (int2*)nbr;

  const int EB2 = (NN + 127) / 128;   // 782 blocks (MFMA kernels)

  k_wtile<<<48, 64, 0, stream>>>(Wenc, Wt);
  k_hist2<<<SBLK, 256, 0, stream>>>(src, dst, cm_f, cm_r);
  k_scan1<<<2 * NBUCK, 256, 0, stream>>>(cm_f, cm_r, btot);
  k_scan2<<<1, 512, 0, stream>>>(btot, bbase_f, bbase_r);
  k_scatter2<<<SBLK, 256, 0, stream>>>(src, dst, wts, cm_f, cm_r,
                                       bbase_f, bbase_r, stg_f, stg_r);
  p_build<<<2 * NBUCK, 256, 0, stream>>>(stg_f, btot, bbase_f, startf, cntf, cvf,
                                         stg_r, btot + NBUCK, bbase_r, startr, cntr, cvr);
  k_enc3<<<EB2, 256, 0, stream>>>(text, Wt, benc, x, xb);

  const int GB = ((NN * 32) + 255) / 256;   // 12500 blocks per direction
  for (int l = 0; l < 2; ++l) {
    k_gather2<<<2 * GB, 256, 0, stream>>>(xb, startf, cntf, cvf, nbf,
                                          startr, cntr, cvr, nbr);
    k_layer<<<EB2, 256, 0, stream>>>(xb, nbf, nbr,
                                     Wsf + l * HID * HID, Wnf + l * HID * HID, bf + l * HID,
                                     Wsr + l * HID * HID, Wnr + l * HID * HID, br + l * HID,
                                     x, xb);
  }
  k_out<<<(BATCH * 64) / 256, 256, 0, stream>>>(x, ids, out);
}

// Round 11
// 600.040 us; speedup vs baseline: 1.0568x; 1.0241x over previous
//
#include <hip/hip_runtime.h>

#define NN 100000
#define NE 1600000
#define HID 64
#define TXT 384
#define BATCH 1024
#define NBUCK 391        // ceil(NN/256)
#define SBLK 256         // scatter/hist blocks
#define EPB ((NE + SBLK - 1) / SBLK)   // edges per block = 6250
#define LDA 40           // k_enc A-tile bf16 stride (80 B)
#define LDK2 72          // k_layer bf16 stride (144 B)

typedef __attribute__((ext_vector_type(8))) short short8;
typedef __attribute__((ext_vector_type(4))) float float4v;

__device__ __forceinline__ ushort f2bf(float f) {
  unsigned u = __float_as_uint(f);
  unsigned r = (u + 0x7fffu + ((u >> 16) & 1u)) >> 16;  // round-to-nearest-even
  return (ushort)r;
}
__device__ __forceinline__ float bf2f(ushort u) {
  return __uint_as_float(((unsigned)u) << 16);
}
__device__ __forceinline__ short8 pack8(float4 a, float4 b) {
  short8 s;
  s[0] = (short)f2bf(a.x); s[1] = (short)f2bf(a.y);
  s[2] = (short)f2bf(a.z); s[3] = (short)f2bf(a.w);
  s[4] = (short)f2bf(b.x); s[5] = (short)f2bf(b.y);
  s[6] = (short)f2bf(b.z); s[7] = (short)f2bf(b.w);
  return s;
}

// ---- P1: per-(block,bucket) histogram matrix --------------------------------
__global__ void k_hist2(const int* __restrict__ src, const int* __restrict__ dst,
                        int* __restrict__ cm_f, int* __restrict__ cm_r) {
  __shared__ int hf[NBUCK], hr[NBUCK];
  const int t = threadIdx.x, blk = blockIdx.x;
  for (int i = t; i < NBUCK; i += 256) { hf[i] = 0; hr[i] = 0; }
  __syncthreads();
  const int e0 = blk * EPB, e1 = min(NE, e0 + EPB);
  for (int e = e0 + t; e < e1; e += 256) {
    atomicAdd(&hf[dst[e] >> 8], 1);
    atomicAdd(&hr[src[e] >> 8], 1);
  }
  __syncthreads();
  for (int i = t; i < NBUCK; i += 256) {
    cm_f[i * SBLK + blk] = hf[i];
    cm_r[i * SBLK + blk] = hr[i];
  }
}

// ---- P2a: per-bucket exclusive scan over the 256 block-counts ---------------
__global__ void k_scan1(int* __restrict__ cm_f, int* __restrict__ cm_r,
                        int* __restrict__ btot) {
  __shared__ int tmp[256];
  const int t = threadIdx.x;
  int b = blockIdx.x;
  int* cm = (b < NBUCK) ? cm_f : cm_r;
  int bucket = (b < NBUCK) ? b : b - NBUCK;
  int* row = cm + bucket * SBLK;
  int v = row[t];
  tmp[t] = v; __syncthreads();
  for (int d = 1; d < 256; d <<= 1) {
    int s = tmp[t]; if (t >= d) s += tmp[t - d];
    __syncthreads(); tmp[t] = s; __syncthreads();
  }
  row[t] = tmp[t] - v;
  if (t == 255) btot[b] = tmp[t];
}

// ---- P2b: exclusive scan of bucket totals -> bucket bases -------------------
__global__ void k_scan2(const int* __restrict__ btot,
                        int* __restrict__ bbase_f, int* __restrict__ bbase_r) {
  __shared__ int tmp[512];
  const int t = threadIdx.x;
  int h = (t < NBUCK) ? btot[t] : 0;
  tmp[t] = h; __syncthreads();
  for (int d = 1; d < 512; d <<= 1) {
    int v = tmp[t]; if (t >= d) v += tmp[t - d];
    __syncthreads(); tmp[t] = v; __syncthreads();
  }
  if (t < NBUCK) bbase_f[t] = tmp[t] - h;
  __syncthreads();
  h = (t < NBUCK) ? btot[NBUCK + t] : 0;
  tmp[t] = h; __syncthreads();
  for (int d = 1; d < 512; d <<= 1) {
    int v = tmp[t]; if (t >= d) v += tmp[t - d];
    __syncthreads(); tmp[t] = v; __syncthreads();
  }
  if (t < NBUCK) bbase_r[t] = tmp[t] - h;
}

// ---- P3: scatter with LDS cursors only (zero global atomics) ----------------
__global__ void k_scatter2(const int* __restrict__ src, const int* __restrict__ dst,
                           const float* __restrict__ w,
                           const int* __restrict__ cm_f, const int* __restrict__ cm_r,
                           const int* __restrict__ bbase_f, const int* __restrict__ bbase_r,
                           int2* __restrict__ stg_f, int2* __restrict__ stg_r) {
  __shared__ int cur_f[NBUCK], cur_r[NBUCK];
  const int t = threadIdx.x, blk = blockIdx.x;
  for (int i = t; i < NBUCK; i += 256) {
    cur_f[i] = bbase_f[i] + cm_f[i * SBLK + blk];
    cur_r[i] = bbase_r[i] + cm_r[i * SBLK + blk];
  }
  __syncthreads();
  const int e0 = blk * EPB, e1 = min(NE, e0 + EPB);
  for (int e = e0 + t; e < e1; e += 256) {
    int s = src[e], d = dst[e];
    int wb = __float_as_int(w[e]);
    int p = atomicAdd(&cur_f[d >> 8], 1);
    stg_f[p] = make_int2(((d & 255) << 24) | s, wb);
    int q = atomicAdd(&cur_r[s >> 8], 1);
    stg_r[q] = make_int2(((s & 255) << 24) | d, wb);
  }
}

// ---- P4: per-bucket CSR finalize + degree-sorted row permutation ------------
__global__ void p_build(const int2* __restrict__ stgf, const int* __restrict__ btotf,
                        const int* __restrict__ bbasef,
                        int* __restrict__ startf, int* __restrict__ cntf,
                        int2* __restrict__ cvf, int* __restrict__ permf,
                        const int2* __restrict__ stgr, const int* __restrict__ btotr,
                        const int* __restrict__ bbaser,
                        int* __restrict__ startr, int* __restrict__ cntr,
                        int2* __restrict__ cvr, int* __restrict__ permr) {
  int b = blockIdx.x;
  const int2* stg; const int* bcnt; const int* bbase;
  int* start; int* cnt; int2* cv; int* perm;
  if (b < NBUCK) { stg = stgf; bcnt = btotf; bbase = bbasef; start = startf; cnt = cntf; cv = cvf; perm = permf; }
  else { b -= NBUCK; stg = stgr; bcnt = btotr; bbase = bbaser; start = startr; cnt = cntr; cv = cvr; perm = permr; }
  const int base = bbase[b];
  const int n = bcnt[b];
  const int t = threadIdx.x;
  __shared__ int hist[256], tmp[256], cur[256], dh[256], dc[256];
  hist[t] = 0;
  perm[b * 256 + t] = -1;
  __syncthreads();
  for (int i = t; i < n; i += 256) {
    unsigned pk = (unsigned)stg[base + i].x;
    atomicAdd(&hist[pk >> 24], 1);
  }
  __syncthreads();
  const int h = hist[t];
  tmp[t] = h; __syncthreads();
  for (int d = 1; d < 256; d <<= 1) {
    int v = tmp[t]; if (t >= d) v += tmp[t - d];
    __syncthreads(); tmp[t] = v; __syncthreads();
  }
  const int excl = tmp[t] - h;
  const int node = (b << 8) + t;
  const bool valid = (node < NN);
  if (valid) { start[node] = base + excl; cnt[node] = h; }
  cur[t] = excl;
  // degree counting-sort -> perm (rows with equal degree land adjacent)
  dh[t] = 0; __syncthreads();
  const int dcap = min(h, 255);
  if (valid) atomicAdd(&dh[dcap], 1);
  __syncthreads();
  int dv = dh[t];
  tmp[t] = dv; __syncthreads();
  for (int d = 1; d < 256; d <<= 1) {
    int v = tmp[t]; if (t >= d) v += tmp[t - d];
    __syncthreads(); tmp[t] = v; __syncthreads();
  }
  dc[t] = tmp[t] - dv;
  __syncthreads();
  if (valid) {
    int pos = atomicAdd(&dc[dcap], 1);
    perm[b * 256 + pos] = node;
  }
  __syncthreads();
  for (int i = t; i < n; i += 256) {
    int2 en = stg[base + i];
    unsigned d8 = ((unsigned)en.x) >> 24;
    int pos = atomicAdd(&cur[d8], 1);
    cv[base + pos] = make_int2(en.x & 0xFFFFFF, en.y);
  }
}

// ---- gather v3: 4 degree-matched rows/wave, 16 lanes/row, 8B loads ----------
__global__ void k_gather3(const ushort* __restrict__ xb,
                          const int* __restrict__ permf, const int* __restrict__ startf,
                          const int* __restrict__ cntf, const int2* __restrict__ cvf,
                          ushort* __restrict__ nbf,
                          const int* __restrict__ permr, const int* __restrict__ startr,
                          const int* __restrict__ cntr, const int2* __restrict__ cvr,
                          ushort* __restrict__ nbr) {
  const int BPD = (NBUCK * 256) / 16;   // 6256 blocks per direction
  int b = blockIdx.x;
  const int *perm, *start, *cnt; const int2* cv; ushort* outp;
  if (b < BPD) { perm = permf; start = startf; cnt = cntf; cv = cvf; outp = nbf; }
  else { b -= BPD; perm = permr; start = startr; cnt = cntr; cv = cvr; outp = nbr; }
  const int lane = threadIdx.x & 63;
  const int wave = threadIdx.x >> 6;
  const int slot = b * 16 + wave * 4 + (lane >> 4);
  const int fl = (lane & 15) * 4;       // ushort offset: 16 lanes x 8 B = 128 B row
  const int row = perm[slot];
  if (row < 0) return;
  const int s = start[row], c = cnt[row];
  const int e = s + c;
  float a0 = 0.f, a1 = 0.f, a2 = 0.f, a3 = 0.f;
  int j = s;
  for (; j + 4 <= e; j += 4) {
    int2 e0 = cv[j], e1 = cv[j + 1], e2 = cv[j + 2], e3 = cv[j + 3];
    uint2 v0 = *(const uint2*)(xb + (size_t)e0.x * 64 + fl);
    uint2 v1 = *(const uint2*)(xb + (size_t)e1.x * 64 + fl);
    uint2 v2 = *(const uint2*)(xb + (size_t)e2.x * 64 + fl);
    uint2 v3 = *(const uint2*)(xb + (size_t)e3.x * 64 + fl);
    float w0 = __int_as_float(e0.y), w1 = __int_as_float(e1.y);
    float w2 = __int_as_float(e2.y), w3 = __int_as_float(e3.y);
    a0 += w0 * bf2f((ushort)v0.x); a1 += w0 * bf2f((ushort)(v0.x >> 16));
    a2 += w0 * bf2f((ushort)v0.y); a3 += w0 * bf2f((ushort)(v0.y >> 16));
    a0 += w1 * bf2f((ushort)v1.x); a1 += w1 * bf2f((ushort)(v1.x >> 16));
    a2 += w1 * bf2f((ushort)v1.y); a3 += w1 * bf2f((ushort)(v1.y >> 16));
    a0 += w2 * bf2f((ushort)v2.x); a1 += w2 * bf2f((ushort)(v2.x >> 16));
    a2 += w2 * bf2f((ushort)v2.y); a3 += w2 * bf2f((ushort)(v2.y >> 16));
    a0 += w3 * bf2f((ushort)v3.x); a1 += w3 * bf2f((ushort)(v3.x >> 16));
    a2 += w3 * bf2f((ushort)v3.y); a3 += w3 * bf2f((ushort)(v3.y >> 16));
  }
  for (; j < e; ++j) {
    int2 ee = cv[j];
    uint2 v = *(const uint2*)(xb + (size_t)ee.x * 64 + fl);
    float ww = __int_as_float(ee.y);
    a0 += ww * bf2f((ushort)v.x); a1 += ww * bf2f((ushort)(v.x >> 16));
    a2 += ww * bf2f((ushort)v.y); a3 += ww * bf2f((ushort)(v.y >> 16));
  }
  float inv = (c > 0) ? 1.0f / (float)c : 0.f;   // DGL mean; zero in-degree -> 0
  uint2 pv;
  pv.x = (uint)f2bf(a0 * inv) | ((uint)f2bf(a1 * inv) << 16);
  pv.y = (uint)f2bf(a2 * inv) | ((uint)f2bf(a3 * inv) << 16);
  *(uint2*)(outp + (size_t)row * 64 + fl) = pv;
}

// ---- W pre-tile: W fp32 [k][n] -> Wt bf16 in MFMA B-fragment layout ---------
__global__ void k_wtile(const float* __restrict__ W, ushort* __restrict__ Wt) {
  int b = blockIdx.x;            // 48 blocks: ch = b>>2, nt = b&3
  int ch = b >> 2, nt = b & 3;
  int lane = threadIdx.x;        // 64
  int quad = lane >> 4, lr = lane & 15;
  short8 s;
  #pragma unroll
  for (int j = 0; j < 8; ++j)
    s[j] = (short)f2bf(W[(ch * 32 + quad * 8 + j) * 64 + nt * 16 + lr]);
  *(short8*)&Wt[((size_t)b * 64 + lane) * 8] = s;
}

// ---- encoder v3: A double-buffered in small LDS, B fragments from L2 --------
__launch_bounds__(256)
__global__ void k_enc3(const float* __restrict__ T, const ushort* __restrict__ Wt,
                       const float* __restrict__ bias,
                       float* __restrict__ x, ushort* __restrict__ xb) {
  __shared__ short As[2][128 * LDA];   // 2 x 10 KB
  const int tid = threadIdx.x;
  const int row0 = blockIdx.x * 128;
  const int wave = tid >> 6, lane = tid & 63;
  const int quad = lane >> 4, lr = lane & 15;
  const int srow = tid >> 1, shalf = (tid & 1) * 16;
  const int grow = min(row0 + srow, NN - 1);
  const float* tp = T + (size_t)grow * TXT + shalf;

  float4 pa0 = *(const float4*)(tp);
  float4 pa1 = *(const float4*)(tp + 4);
  float4 pa2 = *(const float4*)(tp + 8);
  float4 pa3 = *(const float4*)(tp + 12);
  *(short8*)&As[0][srow * LDA + shalf] = pack8(pa0, pa1);
  *(short8*)&As[0][srow * LDA + shalf + 8] = pack8(pa2, pa3);
  pa0 = *(const float4*)(tp + 32);
  pa1 = *(const float4*)(tp + 36);
  pa2 = *(const float4*)(tp + 40);
  pa3 = *(const float4*)(tp + 44);
  __syncthreads();

  const ushort* pw = Wt + lane * 8;
  float4v acc[2][4] = {};
  #pragma unroll
  for (int ch = 0; ch < 12; ++ch) {
    const short* Ac = As[ch & 1];
    short8 af0 = *(const short8*)&Ac[(wave * 32 + lr) * LDA + quad * 8];
    short8 af1 = *(const short8*)&Ac[(wave * 32 + 16 + lr) * LDA + quad * 8];
    #pragma unroll
    for (int nt = 0; nt < 4; ++nt) {
      short8 bfrag = *(const short8*)(pw + (size_t)(ch * 4 + nt) * 512);
      acc[0][nt] = __builtin_amdgcn_mfma_f32_16x16x32_bf16(af0, bfrag, acc[0][nt], 0, 0, 0);
      acc[1][nt] = __builtin_amdgcn_mfma_f32_16x16x32_bf16(af1, bfrag, acc[1][nt], 0, 0, 0);
    }
    if (ch < 11) {
      short* An = As[(ch + 1) & 1];
      *(short8*)&An[srow * LDA + shalf] = pack8(pa0, pa1);
      *(short8*)&An[srow * LDA + shalf + 8] = pack8(pa2, pa3);
      if (ch + 2 < 12) {
        const float* q = tp + (ch + 2) * 32;
        pa0 = *(const float4*)(q);
        pa1 = *(const float4*)(q + 4);
        pa2 = *(const float4*)(q + 8);
        pa3 = *(const float4*)(q + 12);
      }
      __syncthreads();
    }
  }
  #pragma unroll
  for (int nt = 0; nt < 4; ++nt) {
    const int col = nt * 16 + lr;
    const float bcol = bias[col];
    #pragma unroll
    for (int mt = 0; mt < 2; ++mt) {
      #pragma unroll
      for (int r = 0; r < 4; ++r) {
        const int row = row0 + wave * 32 + mt * 16 + quad * 4 + r;
        if (row < NN) {
          float v = acc[mt][nt][r] + bcol;
          x[(size_t)row * 64 + col] = v;
          xb[(size_t)row * 64 + col] = f2bf(v);
        }
      }
    }
  }
}

// ---- fused per-layer combine: x += relu(xb@Wsf + nbf@Wnf + bf)
//                                  + relu(xb@Wsr + nbr@Wnr + br);  xb = bf16(x)
__launch_bounds__(256)
__global__ void k_layer(const ushort* __restrict__ xbin,
                        const ushort* __restrict__ nbf, const ushort* __restrict__ nbr,
                        const float* __restrict__ Wsf, const float* __restrict__ Wnf,
                        const float* __restrict__ bfv,
                        const float* __restrict__ Wsr, const float* __restrict__ Wnr,
                        const float* __restrict__ brv,
                        float* __restrict__ x, ushort* __restrict__ xb) {
  __shared__ short B4[4 * 64 * LDK2];   // Wsf, Wsr, Wnf, Wnr bf16 [n][k] (36 KB)
  __shared__ short As[128 * LDK2];      // one bf16 A tile (18 KB)
  const int tid = threadIdx.x;
  const int row0 = blockIdx.x * 128;
  const int wave = tid >> 6, lane = tid & 63;
  const int quad = lane >> 4, lr = lane & 15;

  {
    const float* wm0 = Wsf; const float* wm1 = Wsr;
    const float* wm2 = Wnf; const float* wm3 = Wnr;
    #pragma unroll
    for (int j = 0; j < 16; ++j) {
      int idx = j * 256 + tid;
      int k = idx >> 6, n = idx & 63;
      B4[0 * 64 * LDK2 + n * LDK2 + k] = (short)f2bf(wm0[idx]);
      B4[1 * 64 * LDK2 + n * LDK2 + k] = (short)f2bf(wm1[idx]);
      B4[2 * 64 * LDK2 + n * LDK2 + k] = (short)f2bf(wm2[idx]);
      B4[3 * 64 * LDK2 + n * LDK2 + k] = (short)f2bf(wm3[idx]);
    }
  }
  const int srow = tid >> 1, half = (tid & 1) * 32;
  const int grow = min(row0 + srow, NN - 1);
  {
    const uint4* s = (const uint4*)(xbin + (size_t)grow * 64 + half);
    uint4* d = (uint4*)&As[srow * LDK2 + half];
    d[0] = s[0]; d[1] = s[1]; d[2] = s[2]; d[3] = s[3];
  }
  const uint4* pf = (const uint4*)(nbf + (size_t)grow * 64 + half);
  uint4 p0 = pf[0], p1 = pf[1], p2 = pf[2], p3 = pf[3];
  __syncthreads();

  float4v accf[2][4] = {}, accr[2][4] = {};
  #pragma unroll
  for (int kk = 0; kk < 64; kk += 32) {
    short8 a0 = *(const short8*)&As[(wave * 32 + lr) * LDK2 + kk + quad * 8];
    short8 a1 = *(const short8*)&As[(wave * 32 + 16 + lr) * LDK2 + kk + quad * 8];
    #pragma unroll
    for (int nt = 0; nt < 4; ++nt) {
      short8 bs = *(const short8*)&B4[0 * 64 * LDK2 + (nt * 16 + lr) * LDK2 + kk + quad * 8];
      accf[0][nt] = __builtin_amdgcn_mfma_f32_16x16x32_bf16(a0, bs, accf[0][nt], 0, 0, 0);
      accf[1][nt] = __builtin_amdgcn_mfma_f32_16x16x32_bf16(a1, bs, accf[1][nt], 0, 0, 0);
      short8 bq = *(const short8*)&B4[1 * 64 * LDK2 + (nt * 16 + lr) * LDK2 + kk + quad * 8];
      accr[0][nt] = __builtin_amdgcn_mfma_f32_16x16x32_bf16(a0, bq, accr[0][nt], 0, 0, 0);
      accr[1][nt] = __builtin_amdgcn_mfma_f32_16x16x32_bf16(a1, bq, accr[1][nt], 0, 0, 0);
    }
  }
  __syncthreads();
  { uint4* d = (uint4*)&As[srow * LDK2 + half]; d[0] = p0; d[1] = p1; d[2] = p2; d[3] = p3; }
  {
    const uint4* pr = (const uint4*)(nbr + (size_t)grow * 64 + half);
    p0 = pr[0]; p1 = pr[1]; p2 = pr[2]; p3 = pr[3];
  }
  __syncthreads();
  #pragma unroll
  for (int kk = 0; kk < 64; kk += 32) {
    short8 a0 = *(const short8*)&As[(wave * 32 + lr) * LDK2 + kk + quad * 8];
    short8 a1 = *(const short8*)&As[(wave * 32 + 16 + lr) * LDK2 + kk + quad * 8];
    #pragma unroll
    for (int nt = 0; nt < 4; ++nt) {
      short8 bs = *(const short8*)&B4[2 * 64 * LDK2 + (nt * 16 + lr) * LDK2 + kk + quad * 8];
      accf[0][nt] = __builtin_amdgcn_mfma_f32_16x16x32_bf16(a0, bs, accf[0][nt], 0, 0, 0);
      accf[1][nt] = __builtin_amdgcn_mfma_f32_16x16x32_bf16(a1, bs, accf[1][nt], 0, 0, 0);
    }
  }
  __syncthreads();
  { uint4* d = (uint4*)&As[srow * LDK2 + half]; d[0] = p0; d[1] = p1; d[2] = p2; d[3] = p3; }
  __syncthreads();
  #pragma unroll
  for (int kk = 0; kk < 64; kk += 32) {
    short8 a0 = *(const short8*)&As[(wave * 32 + lr) * LDK2 + kk + quad * 8];
    short8 a1 = *(const short8*)&As[(wave * 32 + 16 + lr) * LDK2 + kk + quad * 8];
    #pragma unroll
    for (int nt = 0; nt < 4; ++nt) {
      short8 bs = *(const short8*)&B4[3 * 64 * LDK2 + (nt * 16 + lr) * LDK2 + kk + quad * 8];
      accr[0][nt] = __builtin_amdgcn_mfma_f32_16x16x32_bf16(a0, bs, accr[0][nt], 0, 0, 0);
      accr[1][nt] = __builtin_amdgcn_mfma_f32_16x16x32_bf16(a1, bs, accr[1][nt], 0, 0, 0);
    }
  }
  #pragma unroll
  for (int nt = 0; nt < 4; ++nt) {
    const int col = nt * 16 + lr;
    const float bf_c = bfv[col], br_c = brv[col];
    #pragma unroll
    for (int mt = 0; mt < 2; ++mt) {
      #pragma unroll
      for (int r = 0; r < 4; ++r) {
        const int row = row0 + wave * 32 + mt * 16 + quad * 4 + r;
        if (row < NN) {
          size_t idx = (size_t)row * 64 + col;
          float v = x[idx] + fmaxf(accf[mt][nt][r] + bf_c, 0.f)
                           + fmaxf(accr[mt][nt][r] + br_c, 0.f);
          x[idx] = v;
          xb[idx] = f2bf(v);
        }
      }
    }
  }
}

// ---- output gather + L2 normalize -------------------------------------------
__global__ void k_out(const float* __restrict__ x, const int* __restrict__ ids,
                      float* __restrict__ out) {
  int b = (blockIdx.x * blockDim.x + threadIdx.x) >> 6;
  int lane = threadIdx.x & 63;
  if (b >= BATCH) return;
  int row = ids[b];
  float v = x[(size_t)row * 64 + lane];
  float s = v * v;
  #pragma unroll
  for (int m = 1; m < 64; m <<= 1) s += __shfl_xor(s, m);
  out[b * 64 + lane] = v / sqrtf(s);
}

extern "C" void kernel_launch(void* const* d_in, const int* in_sizes, int n_in,
                              void* d_out, int out_size, void* d_ws, size_t ws_size,
                              hipStream_t stream) {
  const float* text = (const float*)d_in[0];
  const float* wts  = (const float*)d_in[1];
  const float* Wenc = (const float*)d_in[2];
  const float* benc = (const float*)d_in[3];
  const float* Wsf  = (const float*)d_in[4];
  const float* Wnf  = (const float*)d_in[5];
  const float* bf   = (const float*)d_in[6];
  const float* Wsr  = (const float*)d_in[7];
  const float* Wnr  = (const float*)d_in[8];
  const float* br   = (const float*)d_in[9];
  const int*   src  = (const int*)d_in[10];
  const int*   dst  = (const int*)d_in[11];
  const int*   ids  = (const int*)d_in[12];
  float* out = (float*)d_out;

  char* ws = (char*)d_ws;
  size_t o = 0;
  auto alloc = [&](size_t f32elems) {
    void* p = ws + o;
    o += f32elems * 4;
    o = (o + 255) & ~(size_t)255;
    return p;
  };
  float*  x   = (float*)alloc((size_t)NN * 64);
  ushort* xb  = (ushort*)alloc((size_t)NN * 32);  // bf16 mirror of x
  ushort* nbf = (ushort*)alloc((size_t)NN * 32);  // bf16 neigh fwd; aliased stage_f
  ushort* nbr = (ushort*)alloc((size_t)NN * 32);  // bf16 neigh rev; aliased stage_r
  ushort* Wt  = (ushort*)alloc(48 * 512 / 2);     // tiled bf16 W_enc (48 KB)
  int2*   cvf = (int2*)alloc((size_t)NE * 2);     // final CSR (col, weight)
  int2*   cvr = (int2*)alloc((size_t)NE * 2);
  int* cm_f    = (int*)alloc((size_t)NBUCK * SBLK);
  int* cm_r    = (int*)alloc((size_t)NBUCK * SBLK);
  int* btot    = (int*)alloc(2 * NBUCK);
  int* bbase_f = (int*)alloc(NBUCK);
  int* bbase_r = (int*)alloc(NBUCK);
  int* startf  = (int*)alloc(NN);
  int* cntf    = (int*)alloc(NN);
  int* startr  = (int*)alloc(NN);
  int* cntr    = (int*)alloc(NN);
  int* permf   = (int*)alloc((size_t)NBUCK * 256);  // degree-sorted row order
  int* permr   = (int*)alloc((size_t)NBUCK * 256);

  int2* stg_f = (int2*)nbf;   // staging dead before gathers write nbf
  int2* stg_r = (int2*)nbr;

  const int EB2 = (NN + 127) / 128;   // 782 blocks (MFMA kernels)

  k_wtile<<<48, 64, 0, stream>>>(Wenc, Wt);
  k_hist2<<<SBLK, 256, 0, stream>>>(src, dst, cm_f, cm_r);
  k_scan1<<<2 * NBUCK, 256, 0, stream>>>(cm_f, cm_r, btot);
  k_scan2<<<1, 512, 0, stream>>>(btot, bbase_f, bbase_r);
  k_scatter2<<<SBLK, 256, 0, stream>>>(src, dst, wts, cm_f, cm_r,
                                       bbase_f, bbase_r, stg_f, stg_r);
  p_build<<<2 * NBUCK, 256, 0, stream>>>(stg_f, btot, bbase_f, startf, cntf, cvf, permf,
                                         stg_r, btot + NBUCK, bbase_r, startr, cntr, cvr, permr);
  k_enc3<<<EB2, 256, 0, stream>>>(text, Wt, benc, x, xb);

  const int GB3 = 2 * ((NBUCK * 256) / 16);   // both directions, 16 rows/block
  for (int l = 0; l < 2; ++l) {
    k_gather3<<<GB3, 256, 0, stream>>>(xb, permf, startf, cntf, cvf, nbf,
                                       permr, startr, cntr, cvr, nbr);
    k_layer<<<EB2, 256, 0, stream>>>(xb, nbf, nbr,
                                     Wsf + l * HID * HID, Wnf + l * HID * HID, bf + l * HID,
                                     Wsr + l * HID * HID, Wnr + l * HID * HID, br + l * HID,
                                     x, xb);
  }
  k_out<<<(BATCH * 64) / 256, 256, 0, stream>>>(x, ids, out);
}